// Round 1
// 123.616 us; speedup vs baseline: 1.0074x; 1.0074x over previous
//
#include <hip/hip_runtime.h>

// SSM DPLR kernel: K[h,l] = 2*Re(C_h . dA_h^l . dB_h), dA = diag(g) + q r^T.
// R5: 16-wave producer/consumer pipeline.
//   l = 64*i + j:  K[64i+j] = 2 Re( C_i . X_j ),  X_j = dA^j dB,  C_i = C M^i, M = dA^64.
//   - waves 2..9  : C-chain producers (8 M-rows each, LDS partial reduce)
//   - waves 10..15,0,1 : output consumers, row i consumed in 8-n slices while chain runs
//   - wave0: tau-solve + Horner (coeffs via readlane, no LDS); wave1: sigma-solve + X rebuild
//   - 2-wide triangular solve (FP-identical composition via w0)
//   - M-build divisions (cinv) hoisted into the serial-phase window on waves 2..9

#define LL 2048

struct C2 { float re, im; };

__device__ __forceinline__ C2 cmul(C2 a, C2 b){ return {a.re*b.re - a.im*b.im, a.re*b.im + a.im*b.re}; }
__device__ __forceinline__ C2 cadd(C2 a, C2 b){ return {a.re+b.re, a.im+b.im}; }
__device__ __forceinline__ C2 csub(C2 a, C2 b){ return {a.re-b.re, a.im-b.im}; }
__device__ __forceinline__ C2 cinv(C2 a){ float s=1.0f/(a.re*a.re+a.im*a.im); return {a.re*s, -a.im*s}; }
__device__ __forceinline__ C2 cscale(float s, C2 a){ return {s*a.re, s*a.im}; }
__device__ __forceinline__ C2 ld2(float2 v){ return {v.x, v.y}; }
__device__ __forceinline__ float2 st2(C2 v){ return make_float2(v.re, v.im); }

template<int CTRL>
__device__ __forceinline__ float dpp_add(float x){
  int t = __builtin_amdgcn_update_dpp(0, __float_as_int(x), CTRL, 0xF, 0xF, true);
  return x + __int_as_float(t);
}
// lane 63 ends with the full 64-lane sum
__device__ __forceinline__ float wave_sum63(float x){
  x = dpp_add<0xB1>(x);   // quad_perm xor1
  x = dpp_add<0x4E>(x);   // quad_perm xor2
  x = dpp_add<0x124>(x);  // row_ror:4
  x = dpp_add<0x128>(x);  // row_ror:8
  x = dpp_add<0x142>(x);  // row_bcast:15
  x = dpp_add<0x143>(x);  // row_bcast:31
  return x;
}
__device__ __forceinline__ float bcast63(float x){
  return __int_as_float(__builtin_amdgcn_readlane(__float_as_int(x), 63));
}
__device__ __forceinline__ float rdlane(float v, int l){
  return __int_as_float(__builtin_amdgcn_readlane(__float_as_int(v), l));
}
// D[m] = S[m-1], lane0 <- 0   (wave_shr:1 = 0x138)
__device__ __forceinline__ float shr1(float x){
  return __int_as_float(__builtin_amdgcn_update_dpp(0, __float_as_int(x), 0x138, 0xF, 0xF, true));
}

// 2-wide triangular-Toeplitz solve: v_j = rhs_j + sum_{i<j} w_{j-1-i} v_i.
// On return lane j holds v_j in (so_re, so_im). Uses v_{j+1} = va_{j+1} + w0*v_j
// (identical arithmetic to two sequential 1-wide iterations).
__device__ __forceinline__ void tri_solve64(const C2 wl, C2 va, const int lane,
                                            float& so_re, float& so_im)
{
    C2 wsh = { shr1(wl.re), shr1(wl.im) };      // w_{m-1}, lane0 = 0
    const float w0r = rdlane(wl.re, 0);
    const float w0i = rdlane(wl.im, 0);
    so_re = 0.0f; so_im = 0.0f;
    for (int j = 0; j < 64; j += 2) {
        const float s0r = rdlane(va.re, j);
        const float s0i = rdlane(va.im, j);
        const float v1r = rdlane(va.re, j + 1);
        const float v1i = rdlane(va.im, j + 1);
        const float s1r = v1r + (w0r*s0r - w0i*s0i);
        const float s1i = v1i + (w0r*s0i + w0i*s0r);
        if (lane == j)     { so_re = s0r; so_im = s0i; }
        if (lane == j + 1) { so_re = s1r; so_im = s1i; }
        const C2 wsh1 = { shr1(wsh.re), shr1(wsh.im) };   // w_{m-2-j}
        va.re += wsh.re*s0r - wsh.im*s0i;
        va.im += wsh.re*s0i + wsh.im*s0r;
        va.re += wsh1.re*s1r - wsh1.im*s1i;
        va.im += wsh1.re*s1i + wsh1.im*s1r;
        wsh.re = shr1(wsh1.re);
        wsh.im = shr1(wsh1.im);
    }
}

__global__ __launch_bounds__(1024) void ssm_dplr_kernel(
    const float* __restrict__ A_real, const float* __restrict__ A_imag,
    const float* __restrict__ B_real, const float* __restrict__ B_imag,
    const float* __restrict__ P_real, const float* __restrict__ P_imag,
    const float* __restrict__ C_real, const float* __restrict__ C_imag,
    const float* __restrict__ log_dt, float* __restrict__ out)
{
    const int h    = blockIdx.x;
    const int t    = threadIdx.x;
    const int lane = t & 63;
    const int wid  = t >> 6;     // wave 0..15

    extern __shared__ char sm[];
    float2* Abuf  = (float2*)sm;              // 64x64: G (powers), later X   [32 KB]
    float2* Cs    = (float2*)(sm + 32768);    // 32x64 C_i rows               [16 KB]
    float2* prtWA = Cs;                       // w/a partials alias Cs (dead then)
    float2* prt   = (float2*)(sm + 49152);    // 2 x (8x64) chain partials    [ 8 KB]
    float2* gA    = (float2*)(sm + 57344);    // smalls, 64 float2 each:
    float2* qA    = gA + 64;
    float2* g64A  = gA + 128;
    float2* TgA   = gA + 192;
    float2* TpA   = gA + 256;
    float2* rqA   = gA + 320;
    float2* rxA   = gA + 384;
    float2* wvA   = gA + 448;
    float2* avA   = gA + 512;
    // LDS total: 57344 + 9*64*8 = 61952 B  (< 64 KB dynamic limit)

    // ---------------- setup (every wave redundantly, per-lane n = lane) ----------------
    const int idx = h * 64 + lane;
    const float dt = expf(log_dt[h]);
    const float c  = 0.5f * dt;

    const C2 lam = { -A_real[idx], -A_imag[idx] };
    const C2 p   = {  P_real[idx],  P_imag[idx] };
    const C2 Bv  = {  B_real[idx],  B_imag[idx] };
    const C2 Cv  = {  C_real[idx],  C_imag[idx] };
    const C2 pc  = { p.re, -p.im };

    const C2 d = cinv(C2{ 1.0f - c*lam.re, -c*lam.im });
    const C2 g = cmul(d, C2{ 1.0f + c*lam.re, c*lam.im });   // diag of dA

    // Sherman-Morrison scalars via DPP wave sums
    C2 sv = cscale(p.re*p.re + p.im*p.im, d);
    C2 uv = cmul(cmul(d, pc), Bv);
    sv.re = bcast63(wave_sum63(sv.re)); sv.im = bcast63(wave_sum63(sv.im));
    uv.re = bcast63(wave_sum63(uv.re)); uv.im = bcast63(wave_sum63(uv.im));

    const C2 beta  = cscale(c, cinv(C2{ 1.0f + c*sv.re, c*sv.im }));
    const C2 bs    = cmul(beta, sv);
    const C2 gamma = { -c*(1.0f - bs.re), c*bs.im };

    const C2 q  = cmul(d, p);
    const C2 r  = cmul(pc, csub(gamma, cmul(beta, g)));
    const C2 x0 = cscale(dt, csub(cmul(d, Bv), cmul(cmul(beta, uv), q)));  // dB

    // power chain
    const C2 g2  = cmul(g,  g);
    const C2 g4  = cmul(g2, g2);
    const C2 g8  = cmul(g4, g4);
    const C2 g16 = cmul(g8, g8);
    const C2 g32 = cmul(g16,g16);
    const C2 g64 = cmul(g32,g32);

    if (wid == 0) {
        gA[lane]   = st2(g);
        qA[lane]   = st2(q);
        g64A[lane] = st2(g64);
        rqA[lane]  = st2(cmul(r, q));
        rxA[lane]  = st2(cmul(r, x0));
    }
    __syncthreads();

    // ---------------- G-gen: G[j][n] = g_n^j, rows j in [4w, 4w+4) ----------------
    {
        C2 cur = {1.0f, 0.0f};
        if (wid & 1) cur = g4;
        if (wid & 2) cur = cmul(cur, g8);
        if (wid & 4) cur = cmul(cur, g16);
        if (wid & 8) cur = cmul(cur, g32);          // g^(4*wid)
        #pragma unroll
        for (int jj = 0; jj < 4; ++jj) {
            const int j = 4*wid + jj;
            Abuf[j*64 + ((lane + j) & 63)] = st2(cur);   // rotated columns
            cur = cmul(cur, g);
        }
    }
    __syncthreads();

    // ---------------- w_j, a_j via transpose-sum (lane = j) ----------------
    {
        C2 accw = {0,0}, acca = {0,0};
        #pragma unroll
        for (int kk = 0; kk < 4; ++kk) {
            const int n = 4*wid + kk;
            const C2 Gv = ld2(Abuf[lane*64 + ((n + lane) & 63)]);
            const C2 fq = ld2(rqA[n]);      // uniform
            const C2 fx = ld2(rxA[n]);      // uniform
            accw = cadd(accw, cmul(Gv, fq));
            acca = cadd(acca, cmul(Gv, fx));
        }
        prtWA[wid*64 + lane]        = st2(accw);
        prtWA[1024 + wid*64 + lane] = st2(acca);
    }
    __syncthreads();
    if (t < 64) {
        C2 sw = {0,0}, sa = {0,0};
        #pragma unroll
        for (int w2 = 0; w2 < 16; ++w2) {
            sw = cadd(sw, ld2(prtWA[w2*64 + t]));
            sa = cadd(sa, ld2(prtWA[1024 + w2*64 + t]));
        }
        wvA[t] = st2(sw);
        avA[t] = st2(sa);
    }
    __syncthreads();

    // ---------------- serial window ----------------
    // wave0: tau-solve + Horner(T,T') from own registers
    // wave1: sigma-solve + X rebuild from own registers
    // waves 2..9: M-prep (the divisions, need only g) ; wave10: C_0 row
    C2 idmk[8], uk[8];
    C2 g63d = {0,0};
    if (wid == 0) {
        const C2 wl = ld2(wvA[lane]);
        float tau_re, tau_im;
        tri_solve64(wl, wl, lane, tau_re, tau_im);      // rhs = w -> tau
        // T(z) = sum_{i=0}^{62} tau_i z^{63-i} = z * P(z); P, P' by Horner
        C2 pp = { rdlane(tau_re, 0), rdlane(tau_im, 0) };
        C2 dd = {0,0};
        for (int i = 1; i <= 62; ++i) {
            const C2 ti = { rdlane(tau_re, i), rdlane(tau_im, i) };
            dd = cadd(cmul(dd, g), pp);
            pp = cadd(cmul(pp, g), ti);
        }
        TgA[lane] = st2(cmul(g, pp));              // T(g)
        TpA[lane] = st2(cadd(pp, cmul(g, dd)));    // T'(g) = P + z P'
    } else if (wid == 1) {
        const C2 wl = ld2(wvA[lane]);
        float sg_re, sg_im;
        tri_solve64(wl, ld2(avA[lane]), lane, sg_re, sg_im);   // rhs = a -> sigma
        // X_0 = dB; X_{j+1} = g.*X_j + sigma_j * q
        C2 x = x0;
        for (int j = 0; j < 64; ++j) {
            Abuf[j*64 + ((lane + j) & 63)] = st2(x);
            const float sjr = rdlane(sg_re, j);
            const float sji = rdlane(sg_im, j);
            const float nr = g.re*x.re - g.im*x.im + sjr*q.re - sji*q.im;
            const float ni = g.re*x.im + g.im*x.re + sjr*q.im + sji*q.re;
            x.re = nr; x.im = ni;
        }
    } else if (wid < 10) {
        const int pp_ = wid - 2;
        #pragma unroll
        for (int k = 0; k < 8; ++k) {
            const int n = 8*pp_ + k;
            const C2 gn = ld2(gA[n]);              // uniform
            idmk[k] = cinv(csub(gn, g));           // n==lane -> inf/NaN, diag overwritten
            uk[k]   = csub(ld2(g64A[n]), g64);
        }
        if ((lane >> 3) == pp_) g63d = cmul(g64, cinv(g));
    } else if (wid == 10) {
        Cs[lane] = st2(Cv);                        // C_0 row for consumers
    }
    __syncthreads();

    // ---------------- M finish (producers): Mk[k] = M[8p+k][m], m = lane ----------------
    // M[n][m] = d_{nm} g64_n + q_n r_m [ (g64_n - g64_m) + (T(g_n) - T(g_m)) ] / (g_n - g_m)
    // M[n][n] = g64_n + q_n r_n ( 64 g_n^63 + T'(g_n) )
    const bool isProd = (wid >= 2 && wid < 10);
    const int  pr     = wid - 2;                    // producer index 0..7
    C2 Mk[8];
    if (isProd) {
        const C2 Tgm = ld2(TgA[lane]);
        #pragma unroll
        for (int k = 0; k < 8; ++k) {
            const int n = 8*pr + k;
            const C2 qn  = ld2(qA[n]);             // uniform
            const C2 Tgn = ld2(TgA[n]);
            const C2 num = cmul(r, cadd(uk[k], csub(Tgn, Tgm)));
            Mk[k] = cmul(cmul(qn, num), idmk[k]);
        }
        if ((lane >> 3) == pr) {                   // diagonal element owned by this thread
            const int k0 = lane & 7;
            const C2 Tp = ld2(TpA[lane]);
            const C2 S  = cmul(r, cadd(cscale(64.0f, g63d), Tp));
            Mk[k0] = cadd(g64, cmul(q, S));
        }
    }

    // ---------------- fused chain + output pipeline ----------------
    // producers (waves 2..9): step s<31 computes C_{s+1}; wave2 publishes to Cs.
    // consumers (waves 10..15 -> c=0..5, wave0 -> c=6, wave1 -> c=7):
    //   row r (r&7 == c) consumed in 8-n slices over steps r..r+7.
    const bool isCons = !isProd;
    const int  cix    = (wid >= 10) ? (wid - 10) : (wid + 6);
    C2 Ci = Cv;                                    // C_0 (per-lane n)
    float accK = 0.0f;
    float* outh = out + h * LL;

    for (int s = 0; s < 39; ++s) {
        if (isProd && s < 31) {
            C2 acc = {0,0};
            #pragma unroll
            for (int k = 0; k < 8; ++k) {
                const float cr = rdlane(Ci.re, 8*pr + k);
                const float cim= rdlane(Ci.im, 8*pr + k);
                acc.re += cr*Mk[k].re - cim*Mk[k].im;
                acc.im += cr*Mk[k].im + cim*Mk[k].re;
            }
            prt[(s & 1)*512 + pr*64 + lane] = st2(acc);
        }
        __syncthreads();
        if (isProd && s < 31) {
            C2 nc = {0,0};
            #pragma unroll
            for (int w2 = 0; w2 < 8; ++w2) {
                const float2 pv = prt[(s & 1)*512 + w2*64 + lane];
                nc.re += pv.x; nc.im += pv.y;
            }
            Ci = nc;
            if (pr == 0) Cs[(s + 1)*64 + lane] = st2(Ci);   // visible after next barrier
        } else if (isCons && s >= cix) {
            const int kk = (s - cix) >> 3;
            if (kk < 4) {
                const int rr    = cix + (kk << 3);          // output row i = rr
                const int slice = (s - cix) & 7;
                const int n0    = slice << 3;
                #pragma unroll
                for (int nn = 0; nn < 8; ++nn) {
                    const int n = n0 + nn;
                    const float2 cv = Cs[rr*64 + n];                   // uniform
                    const float2 xv = Abuf[lane*64 + ((n + lane) & 63)];
                    accK += cv.x*xv.x - cv.y*xv.y;
                }
                if (slice == 7) {
                    outh[rr*64 + lane] = 2.0f * accK;
                    accK = 0.0f;
                }
            }
        }
    }
}

extern "C" void kernel_launch(void* const* d_in, const int* in_sizes, int n_in,
                              void* d_out, int out_size, void* d_ws, size_t ws_size,
                              hipStream_t stream) {
    const float* A_real = (const float*)d_in[0];
    const float* A_imag = (const float*)d_in[1];
    const float* B_real = (const float*)d_in[2];
    const float* B_imag = (const float*)d_in[3];
    const float* P_real = (const float*)d_in[4];
    const float* P_imag = (const float*)d_in[5];
    const float* C_real = (const float*)d_in[6];
    const float* C_imag = (const float*)d_in[7];
    const float* log_dt = (const float*)d_in[8];
    float* out = (float*)d_out;

    const size_t lds = 57344 + 576*sizeof(float2);   // 61952 B
    ssm_dplr_kernel<<<256, 1024, lds, stream>>>(
        A_real, A_imag, B_real, B_imag, P_real, P_imag,
        C_real, C_imag, log_dt, out);
}